// Round 1
// baseline (754.071 us; speedup 1.0000x reference)
//
#include <hip/hip_runtime.h>
#include <math.h>

#define NDIM 128   // in_dim = hid = out_dim
#define H2   256   // 2*hid
#define MAXG 2
#define TPE  8192  // edges per bin tile
#define NBKMAX 512 // max buckets (N <= 65536, 128 nodes/bucket)

typedef __attribute__((ext_vector_type(8))) short bf16x8;
typedef __attribute__((ext_vector_type(4))) float f32x4;

__device__ __forceinline__ unsigned short f2bf(float f) {
    unsigned int u = __float_as_uint(f);
    u += 0x7fffu + ((u >> 16) & 1u);           // RNE
    return (unsigned short)(u >> 16);
}
__device__ __forceinline__ float bf2f(unsigned short h) {
    return __uint_as_float(((unsigned int)h) << 16);
}
__device__ __forceinline__ void split2(float f, unsigned short& h, unsigned short& l) {
    h = f2bf(f);
    l = f2bf(f - bf2f(h));
}

// ================= binned edge build (no global atomics) =================
struct BinArgs {
    const int* src[MAXG]; const int* dst[MAXG];
    int* histD[MAXG]; int* histS[MAXG];     // [NT][NBK] counts -> global run offsets
    int* totD[MAXG];  int* baseD[MAXG];
    int* totS[MAXG];  int* baseS[MAXG];
    unsigned int* pairs[MAXG];              // dst-binned packed (dl<<16|src)
    unsigned short* srcS[MAXG];             // src-binned bare src ids
    int E[MAXG]; int NBK; int NT; int n;
};

__global__ __launch_bounds__(256) void binA(BinArgs a) {
    __shared__ int cntD[NBKMAX], cntS[NBKMAX];
    int g = blockIdx.y, t = blockIdx.x, tid = threadIdx.x;
    for (int b = tid; b < NBKMAX; b += 256) { cntD[b] = 0; cntS[b] = 0; }
    __syncthreads();
    int E = a.E[g];
    int base = t * TPE;
#pragma unroll
    for (int k = 0; k < TPE / 256; ++k) {
        int e = base + k * 256 + tid;
        if (e < E) {
            atomicAdd(&cntD[a.dst[g][e] >> 7], 1);
            atomicAdd(&cntS[a.src[g][e] >> 7], 1);
        }
    }
    __syncthreads();
    for (int b = tid; b < a.NBK; b += 256) {
        a.histD[g][t * a.NBK + b] = cntD[b];
        a.histS[g][t * a.NBK + b] = cntS[b];
    }
}

// fused: per-bucket totals + exclusive scan + rewrite hist to global run offsets
__global__ __launch_bounds__(512) void binB(BinArgs a) {
    int g = blockIdx.y, side = blockIdx.z;
    int* hist = side ? a.histS[g] : a.histD[g];
    int* tot  = side ? a.totS[g]  : a.totD[g];
    int* base = side ? a.baseS[g] : a.baseD[g];
    __shared__ int s[512];
    int b = threadIdx.x;
    int v = 0;
    if (b < a.NBK)
        for (int t = 0; t < a.NT; ++t) v += hist[t * a.NBK + b];
    s[b] = v;
    __syncthreads();
    for (int off = 1; off < 512; off <<= 1) {
        int u = (b >= off) ? s[b - off] : 0;
        __syncthreads();
        s[b] += u;
        __syncthreads();
    }
    int excl = s[b] - v;
    if (b < a.NBK) {
        tot[b] = v;
        base[b] = excl;
        int run = excl;
        for (int t = 0; t < a.NT; ++t) {
            int h = hist[t * a.NBK + b];
            hist[t * a.NBK + b] = run;
            run += h;
        }
    }
}

__global__ __launch_bounds__(256) void binC(BinArgs a) {
    __shared__ int offD[NBKMAX], offS[NBKMAX];
    int g = blockIdx.y, t = blockIdx.x, tid = threadIdx.x;
    for (int b = tid; b < a.NBK; b += 256) {
        offD[b] = a.histD[g][t * a.NBK + b];
        offS[b] = a.histS[g][t * a.NBK + b];
    }
    __syncthreads();
    int E = a.E[g];
    int base = t * TPE;
    unsigned int* pairs = a.pairs[g];
    unsigned short* ss = a.srcS[g];
#pragma unroll
    for (int k = 0; k < TPE / 256; ++k) {
        int e = base + k * 256 + tid;
        if (e < E) {
            int s = a.src[g][e], d = a.dst[g][e];
            int pos = atomicAdd(&offD[d >> 7], 1);
            pairs[pos] = ((unsigned int)(d & 127) << 16) | (unsigned int)s;
            int posS = atomicAdd(&offS[s >> 7], 1);
            ss[posS] = (unsigned short)s;
        }
    }
}

// fused: out-degree hist (-> ns) + per-bucket counting sort (-> CSR, nd, u16 edges)
struct FinArgs {
    const unsigned int* pairs[MAXG];
    const unsigned short* srcS[MAXG];
    const int* totD[MAXG]; const int* baseD[MAXG];
    const int* totS[MAXG]; const int* baseS[MAXG];
    int* row_ptr[MAXG]; int* row_end[MAXG];
    unsigned short* edge_srt[MAXG];
    float* ns[MAXG]; float* nd[MAXG];
    int n;
};

__global__ __launch_bounds__(256) void finalize(FinArgs a) {
    __shared__ int cnt[128], hist[128], scn[128], cur[128];
    int g = blockIdx.y, bkt = blockIdx.x, tid = threadIdx.x;
    if (tid < 128) { cnt[tid] = 0; hist[tid] = 0; }
    __syncthreads();
    // --- out-degree from src-binned segment -> ns ---
    {
        int base = a.baseS[g][bkt], tot = a.totS[g][bkt];
        const unsigned short* ss = a.srcS[g];
        for (int i = tid; i < tot; i += 256)
            atomicAdd(&cnt[ss[base + i] & 127], 1);
    }
    // --- in-degree hist of dst-binned pairs ---
    int cntE = a.totD[g][bkt], base = a.baseD[g][bkt];
    const unsigned int* pp = a.pairs[g] + base;
    for (int i = tid; i < cntE; i += 256)
        atomicAdd(&hist[pp[i] >> 16], 1);
    __syncthreads();
    if (tid < 128) {
        int node = bkt * 128 + tid;
        if (node < a.n) {
            int c = cnt[tid];
            a.ns[g][node] = rsqrtf((float)(c > 1 ? c : 1));
        }
        scn[tid] = hist[tid];
    }
    __syncthreads();
    for (int off = 1; off < 128; off <<= 1) {
        int v = (tid < 128 && tid >= off) ? scn[tid - off] : 0;
        __syncthreads();
        if (tid < 128) scn[tid] += v;
        __syncthreads();
    }
    if (tid < 128) {
        int incl = scn[tid];
        int h = hist[tid];
        cur[tid] = incl - h;
        int node = bkt * 128 + tid;
        if (node < a.n) {
            a.row_ptr[g][node] = base + incl - h;
            a.row_end[g][node] = base + incl;
            a.nd[g][node] = rsqrtf((float)(h > 1 ? h : 1));
        }
    }
    __syncthreads();
    for (int i = tid; i < cntE; i += 256) {
        unsigned int p = pp[i];
        int pos = atomicAdd(&cur[p >> 16], 1);
        a.edge_srt[g][base + pos] = (unsigned short)(p & 0xFFFF);
    }
}

// ===== gather-aggregate, half-wave/row =====
// use_sns: acc += X[src] * ns[src]  (prescale folded in; X = raw feat)
// else:    acc += X[src]            (X already has ns folded upstream)
struct GatherArgs {
    const float* X[MAXG];
    const int* row_ptr[MAXG]; const int* row_end[MAXG];
    const unsigned short* edge_src[MAXG];
    const float* nd[MAXG];
    const float* sns[MAXG];
    unsigned short* outH[MAXG]; unsigned short* outL[MAXG];
    const float* bias; int use_nd; int use_sns; int n;
};

__global__ __launch_bounds__(256) void gather_split_b(GatherArgs a) {
    int g = blockIdx.y;
    int half = threadIdx.x >> 5;
    int lane = threadIdx.x & 31;
    int r = blockIdx.x * 8 + half;
    if (r >= a.n) return;
    int j = a.row_ptr[g][r];
    int end = a.row_end[g][r];
    const unsigned short* ep = a.edge_src[g];
    const float* X = a.X[g];
    const float* sns = a.sns[g];
    int base = lane * 4;
    float4 acc = make_float4(0.f, 0.f, 0.f, 0.f);
    if (a.use_sns) {
        for (; j + 3 < end; j += 4) {
            int s0 = ep[j], s1 = ep[j + 1], s2 = ep[j + 2], s3 = ep[j + 3];
            float n0 = sns[s0], n1 = sns[s1], n2 = sns[s2], n3 = sns[s3];
            float4 v0 = *(const float4*)(X + (size_t)s0 * NDIM + base);
            float4 v1 = *(const float4*)(X + (size_t)s1 * NDIM + base);
            float4 v2 = *(const float4*)(X + (size_t)s2 * NDIM + base);
            float4 v3 = *(const float4*)(X + (size_t)s3 * NDIM + base);
            acc.x = fmaf(v0.x, n0, fmaf(v1.x, n1, fmaf(v2.x, n2, fmaf(v3.x, n3, acc.x))));
            acc.y = fmaf(v0.y, n0, fmaf(v1.y, n1, fmaf(v2.y, n2, fmaf(v3.y, n3, acc.y))));
            acc.z = fmaf(v0.z, n0, fmaf(v1.z, n1, fmaf(v2.z, n2, fmaf(v3.z, n3, acc.z))));
            acc.w = fmaf(v0.w, n0, fmaf(v1.w, n1, fmaf(v2.w, n2, fmaf(v3.w, n3, acc.w))));
        }
        for (; j < end; ++j) {
            int s0 = ep[j];
            float n0 = sns[s0];
            float4 v0 = *(const float4*)(X + (size_t)s0 * NDIM + base);
            acc.x = fmaf(v0.x, n0, acc.x); acc.y = fmaf(v0.y, n0, acc.y);
            acc.z = fmaf(v0.z, n0, acc.z); acc.w = fmaf(v0.w, n0, acc.w);
        }
    } else {
        for (; j + 3 < end; j += 4) {
            int s0 = ep[j], s1 = ep[j + 1], s2 = ep[j + 2], s3 = ep[j + 3];
            float4 v0 = *(const float4*)(X + (size_t)s0 * NDIM + base);
            float4 v1 = *(const float4*)(X + (size_t)s1 * NDIM + base);
            float4 v2 = *(const float4*)(X + (size_t)s2 * NDIM + base);
            float4 v3 = *(const float4*)(X + (size_t)s3 * NDIM + base);
            acc.x += v0.x + v1.x + v2.x + v3.x;
            acc.y += v0.y + v1.y + v2.y + v3.y;
            acc.z += v0.z + v1.z + v2.z + v3.z;
            acc.w += v0.w + v1.w + v2.w + v3.w;
        }
        for (; j < end; ++j) {
            int s0 = ep[j];
            float4 v0 = *(const float4*)(X + (size_t)s0 * NDIM + base);
            acc.x += v0.x; acc.y += v0.y; acc.z += v0.z; acc.w += v0.w;
        }
    }
    float v[4] = {acc.x, acc.y, acc.z, acc.w};
    if (a.use_nd) {
        float s = a.nd[g][r];
#pragma unroll
        for (int i = 0; i < 4; ++i)
            v[i] = fmaxf(v[i] * s + a.bias[base + i], 0.f);
    }
    unsigned short h[4], l[4];
#pragma unroll
    for (int i = 0; i < 4; ++i) split2(v[i], h[i], l[i]);
    *(ushort4*)(a.outH[g] + (size_t)r * NDIM + base) = make_ushort4(h[0], h[1], h[2], h[3]);
    *(ushort4*)(a.outL[g] + (size_t)r * NDIM + base) = make_ushort4(l[0], l[1], l[2], l[3]);
}

// ================= weight prep: all 4 weights, transposed + split =================
__global__ void wprep_all(const float* __restrict__ W1, const float* __restrict__ W2,
                          const float* __restrict__ F1, const float* __restrict__ F2,
                          unsigned short* __restrict__ W1h, unsigned short* __restrict__ W1l,
                          unsigned short* __restrict__ W2h, unsigned short* __restrict__ W2l,
                          unsigned short* __restrict__ F1h, unsigned short* __restrict__ F1l,
                          unsigned short* __restrict__ F2h, unsigned short* __restrict__ F2l) {
    int i = blockIdx.x * 256 + threadIdx.x;
    const float* Wsrc; unsigned short *Hd, *Ld; int K, Nc, idx;
    if (i < 32768)       { Wsrc = W1; Hd = W1h; Ld = W1l; K = 128; Nc = 256; idx = i; }
    else if (i < 65536)  { Wsrc = W2; Hd = W2h; Ld = W2l; K = 256; Nc = 128; idx = i - 32768; }
    else if (i < 81920)  { Wsrc = F1; Hd = F1h; Ld = F1l; K = 128; Nc = 128; idx = i - 65536; }
    else                 { Wsrc = F2; Hd = F2h; Ld = F2l; K = 128; Nc = 128; idx = i - 81920; }
    int k = idx / Nc, n = idx % Nc;
    unsigned short h, l;
    split2(Wsrc[idx], h, l);
    Hd[n * K + k] = h;
    Ld[n * K + k] = l;
}

// ====== split-bf16 MFMA GEMM, LDS-free / barrier-free, fragments from global ======
// A is row-major [M][K] (split h/l); B is [Nc][K] (transposed, split h/l).
// A-fragment: 16 lanes read 16 consecutive rows, 16B contiguous each (L1-shared by
// the 4 waves). B is <=128KB total, L2-resident across all blocks.
struct GemmArgs {
    const unsigned short* Ah[MAXG]; const unsigned short* Al[MAXG];
    const unsigned short* Bh; const unsigned short* Bl;
    float* C[MAXG]; unsigned short* CH[MAXG]; unsigned short* CL[MAXG];
    const float* rsOut[MAXG]; const float* bOut;
    int M, K, Nc, act, has_rs, has_b, split_out;
};

template <int KT>
__global__ __launch_bounds__(256) void mfma_gemm_r(GemmArgs a) {
    int g = blockIdx.z;
    const unsigned short* __restrict__ Ah_g = a.Ah[g];
    const unsigned short* __restrict__ Al_g = a.Al[g];
    const unsigned short* __restrict__ Bh = a.Bh;
    const unsigned short* __restrict__ Bl = a.Bl;

    int tid  = threadIdx.x;
    int wave = tid >> 6, lane = tid & 63;
    int quad = lane >> 4, l16 = lane & 15;
    int rowBase = blockIdx.x * 64;
    int colBase = blockIdx.y * 128;
    int M = a.M, Nc = a.Nc;

    f32x4 acc[4][2] = {};

    // per-lane element offsets; OOB rows clamped (they only feed C rows we skip)
    size_t aoff[4];
#pragma unroll
    for (int i = 0; i < 4; ++i) {
        int row = rowBase + i * 16 + l16;
        if (row > M - 1) row = M - 1;
        aoff[i] = (size_t)row * KT + quad * 8;
    }
    size_t boff[2];
#pragma unroll
    for (int j = 0; j < 2; ++j)
        boff[j] = (size_t)(colBase + wave * 32 + j * 16 + l16) * KT + quad * 8;

#pragma unroll
    for (int kt = 0; kt < KT / 32; ++kt) {
        int k0 = kt * 32;
        bf16x8 af[4], alf[4], bhf[2], blf[2];
#pragma unroll
        for (int i = 0; i < 4; ++i) {
            af[i]  = *(const bf16x8*)(Ah_g + aoff[i] + k0);
            alf[i] = *(const bf16x8*)(Al_g + aoff[i] + k0);
        }
#pragma unroll
        for (int j = 0; j < 2; ++j) {
            bhf[j] = *(const bf16x8*)(Bh + boff[j] + k0);
            blf[j] = *(const bf16x8*)(Bl + boff[j] + k0);
        }
#pragma unroll
        for (int i = 0; i < 4; ++i)
#pragma unroll
            for (int j = 0; j < 2; ++j) {
                acc[i][j] = __builtin_amdgcn_mfma_f32_16x16x32_bf16(af[i],  bhf[j], acc[i][j], 0, 0, 0);
                acc[i][j] = __builtin_amdgcn_mfma_f32_16x16x32_bf16(alf[i], bhf[j], acc[i][j], 0, 0, 0);
                acc[i][j] = __builtin_amdgcn_mfma_f32_16x16x32_bf16(af[i],  blf[j], acc[i][j], 0, 0, 0);
            }
    }

    // epilogue: C/D layout col=lane&15, row=quad*4+reg
#pragma unroll
    for (int i = 0; i < 4; ++i) {
#pragma unroll
        for (int r = 0; r < 4; ++r) {
            int row = rowBase + i * 16 + quad * 4 + r;
            if (row >= M) continue;
            float rs = a.has_rs ? a.rsOut[g][row] : 1.0f;
#pragma unroll
            for (int j = 0; j < 2; ++j) {
                int col = colBase + wave * 32 + j * 16 + l16;
                float v = acc[i][j][r] * rs;
                if (a.has_b) v += a.bOut[col];
                if (a.act == 1) v = fmaxf(v, 0.f);
                else if (a.act == 2) v = v > 0.f ? v : expm1f(v);
                if (a.split_out) {
                    unsigned short h, l;
                    split2(v, h, l);
                    a.CH[g][(size_t)row * Nc + col] = h;
                    a.CL[g][(size_t)row * Nc + col] = l;
                } else {
                    a.C[g][(size_t)row * Nc + col] = v;
                }
            }
        }
    }
}

extern "C" void kernel_launch(void* const* d_in, const int* in_sizes, int n_in,
                              void* d_out, int out_size, void* d_ws, size_t ws_size,
                              hipStream_t stream) {
    const float* feat[2] = {(const float*)d_in[0], (const float*)d_in[1]};
    const int*   ei[2]   = {(const int*)d_in[2], (const int*)d_in[3]};
    const float* W1   = (const float*)d_in[4];
    const float* b1   = (const float*)d_in[5];
    const float* W2   = (const float*)d_in[6];
    const float* b2   = (const float*)d_in[7];
    const float* fc1W = (const float*)d_in[8];
    const float* fc1b = (const float*)d_in[9];
    const float* fc2W = (const float*)d_in[10];
    const float* fc2b = (const float*)d_in[11];
    int N = in_sizes[0] / NDIM;     // 50000 (< 65536: u16 node-id packing valid)
    float* out = (float*)d_out;

    int Emax = 0;
    for (int g = 0; g < 2; ++g) { int E = in_sizes[2 + g] / 2; if (E > Emax) Emax = E; }
    int NBK = (N + 127) / 128;
    int NT  = (Emax + TPE - 1) / TPE;

    // ---- workspace layout ----
    char* p = (char*)d_ws;
    float* ns_[2]; float* nd_[2];
    for (int i = 0; i < 2; ++i) { ns_[i] = (float*)p; p += (size_t)N * 4; }
    for (int i = 0; i < 2; ++i) { nd_[i] = (float*)p; p += (size_t)N * 4; }
    int* rp_[2]; int* re_[2]; unsigned short* esrt_[2];
    for (int i = 0; i < 2; ++i) { rp_[i] = (int*)p; p += (size_t)N * 4; }
    for (int i = 0; i < 2; ++i) { re_[i] = (int*)p; p += (size_t)N * 4; }
    for (int i = 0; i < 2; ++i) { esrt_[i] = (unsigned short*)p; p += (size_t)Emax * 2; }
    unsigned short* R1[2]; unsigned short* R2[2];
    for (int i = 0; i < 2; ++i) { R1[i] = (unsigned short*)p; p += (size_t)N * NDIM * 2 * 2; }
    for (int i = 0; i < 2; ++i) { R2[i] = (unsigned short*)p; p += (size_t)N * H2 * 2 * 2; }
    unsigned short* W1th = (unsigned short*)p; p += (size_t)NDIM * H2 * 2;
    unsigned short* W1tl = (unsigned short*)p; p += (size_t)NDIM * H2 * 2;
    unsigned short* W2th = (unsigned short*)p; p += (size_t)H2 * NDIM * 2;
    unsigned short* W2tl = (unsigned short*)p; p += (size_t)H2 * NDIM * 2;
    unsigned short* f1th = (unsigned short*)p; p += (size_t)NDIM * NDIM * 2;
    unsigned short* f1tl = (unsigned short*)p; p += (size_t)NDIM * NDIM * 2;
    unsigned short* f2th = (unsigned short*)p; p += (size_t)NDIM * NDIM * 2;
    unsigned short* f2tl = (unsigned short*)p; p += (size_t)NDIM * NDIM * 2;
    int* tb = (int*)p; p += (size_t)2 * 4 * NBK * 4;   // totD/baseD/totS/baseS per graph

    // aliases with disjoint lifetimes (all within R1/R2):
    //  - histD/histS at R2[i]+0 (dead after binC); pairs at R2[i]+1MB (dead after finalize)
    //  - srcS at R1[i] (dead after finalize; gather1 then writes A1 into R1)
    //  - gather1 reads feat directly (ns folded per-edge) so R2 is untouched until gemm1
    int* histD_[2]; int* histS_[2]; unsigned int* pairs_[2]; unsigned short* srcS_[2];
    for (int i = 0; i < 2; ++i) {
        histD_[i] = (int*)R2[i];
        histS_[i] = (int*)R2[i] + (size_t)NT * NBK;
        pairs_[i] = (unsigned int*)((char*)R2[i] + (1 << 20));  // 1MB offset > hist tables
        srcS_[i]  = (unsigned short*)R1[i];
    }

    BinArgs ba = {};
    ba.NBK = NBK; ba.NT = NT; ba.n = N;
    for (int i = 0; i < 2; ++i) {
        int E = in_sizes[2 + i] / 2;
        ba.src[i] = ei[i]; ba.dst[i] = ei[i] + E; ba.E[i] = E;
        ba.histD[i] = histD_[i]; ba.histS[i] = histS_[i];
        ba.totD[i]  = tb + (size_t)i * 4 * NBK;
        ba.baseD[i] = tb + (size_t)i * 4 * NBK + NBK;
        ba.totS[i]  = tb + (size_t)i * 4 * NBK + 2 * NBK;
        ba.baseS[i] = tb + (size_t)i * 4 * NBK + 3 * NBK;
        ba.pairs[i] = pairs_[i]; ba.srcS[i] = srcS_[i];
    }

    // ---- weight prep + binned edge build ----
    wprep_all<<<384, 256, 0, stream>>>(W1, W2, fc1W, fc2W,
                                       W1th, W1tl, W2th, W2tl, f1th, f1tl, f2th, f2tl);
    binA<<<dim3(NT, 2), 256, 0, stream>>>(ba);
    binB<<<dim3(1, 2, 2), 512, 0, stream>>>(ba);
    binC<<<dim3(NT, 2), 256, 0, stream>>>(ba);

    FinArgs fa = {};
    fa.n = N;
    for (int i = 0; i < 2; ++i) {
        fa.pairs[i] = pairs_[i]; fa.srcS[i] = srcS_[i];
        fa.totD[i] = ba.totD[i]; fa.baseD[i] = ba.baseD[i];
        fa.totS[i] = ba.totS[i]; fa.baseS[i] = ba.baseS[i];
        fa.row_ptr[i] = rp_[i]; fa.row_end[i] = re_[i];
        fa.edge_srt[i] = esrt_[i];
        fa.ns[i] = ns_[i]; fa.nd[i] = nd_[i];
    }
    finalize<<<dim3(NBK, 2), 256, 0, stream>>>(fa);

    // ---- per-graph buffer aliases ----
    unsigned short *A1h[2], *A1l[2], *X1h[2], *X1l[2], *Gh[2], *Gl[2], *Zh[2], *Zl[2];
    float* T[2];
    for (int i = 0; i < 2; ++i) {
        A1h[i] = R1[i]; A1l[i] = R1[i] + (size_t)N * NDIM;
        T[i]   = (float*)R1[i];
        Zh[i]  = R1[i]; Zl[i]  = R1[i] + (size_t)N * NDIM;
        X1h[i] = R2[i]; X1l[i] = R2[i] + (size_t)N * H2;
        Gh[i]  = R2[i]; Gl[i]  = R2[i] + (size_t)N * NDIM;
    }

    int ggrid = (N + 7) / 8;
    int mgrid = (N + 63) / 64;

    // ---- gather1: A1 = split(sum feat[src] * ns[src]) ----
    GatherArgs ga = {};
    ga.n = N; ga.use_nd = 0; ga.use_sns = 1; ga.bias = b2;
    for (int i = 0; i < 2; ++i) {
        ga.X[i] = feat[i];
        ga.row_ptr[i] = rp_[i]; ga.row_end[i] = re_[i]; ga.edge_src[i] = esrt_[i];
        ga.nd[i] = nd_[i]; ga.sns[i] = ns_[i];
        ga.outH[i] = A1h[i]; ga.outL[i] = A1l[i];
    }
    gather_split_b<<<dim3(ggrid, 2), 256, 0, stream>>>(ga);

    // ---- gemm1: X1 = relu(A1 @ W1 * nd + b1), split out ----
    GemmArgs g1 = {};
    g1.Bh = W1th; g1.Bl = W1tl; g1.bOut = b1;
    g1.M = N; g1.K = NDIM; g1.Nc = H2; g1.act = 1; g1.has_rs = 1; g1.has_b = 1; g1.split_out = 1;
    for (int i = 0; i < 2; ++i) {
        g1.Ah[i] = A1h[i]; g1.Al[i] = A1l[i];
        g1.CH[i] = X1h[i]; g1.CL[i] = X1l[i]; g1.rsOut[i] = nd_[i];
    }
    mfma_gemm_r<128><<<dim3(mgrid, H2 / 128, 2), 256, 0, stream>>>(g1);

    // ---- gemm2: T = (X1 @ W2) * ns, fp32 out (ns folded here so gather2 is a pure sum) ----
    GemmArgs g2 = {};
    g2.Bh = W2th; g2.Bl = W2tl;
    g2.M = N; g2.K = H2; g2.Nc = NDIM; g2.act = 0; g2.has_rs = 1; g2.has_b = 0; g2.split_out = 0;
    for (int i = 0; i < 2; ++i) {
        g2.Ah[i] = X1h[i]; g2.Al[i] = X1l[i]; g2.C[i] = T[i]; g2.rsOut[i] = ns_[i];
    }
    mfma_gemm_r<256><<<dim3(mgrid, 1, 2), 256, 0, stream>>>(g2);

    // ---- gather2: G = split(relu(sum T[src] * nd + b2)) ----
    GatherArgs gb = ga;
    gb.use_nd = 1; gb.use_sns = 0;
    for (int i = 0; i < 2; ++i) {
        gb.X[i] = T[i];
        gb.outH[i] = Gh[i]; gb.outL[i] = Gl[i];
    }
    gather_split_b<<<dim3(ggrid, 2), 256, 0, stream>>>(gb);

    // ---- gemm3: Z = elu(G @ fc1W + fc1b), split out ----
    GemmArgs g3 = {};
    g3.Bh = f1th; g3.Bl = f1tl; g3.bOut = fc1b;
    g3.M = N; g3.K = NDIM; g3.Nc = NDIM; g3.act = 2; g3.has_rs = 0; g3.has_b = 1; g3.split_out = 1;
    for (int i = 0; i < 2; ++i) {
        g3.Ah[i] = Gh[i]; g3.Al[i] = Gl[i];
        g3.CH[i] = Zh[i]; g3.CL[i] = Zl[i];
    }
    mfma_gemm_r<128><<<dim3(mgrid, 1, 2), 256, 0, stream>>>(g3);

    // ---- gemm4: out = Z @ fc2W + fc2b, fp32 out ----
    GemmArgs g4 = {};
    g4.Bh = f2th; g4.Bl = f2tl; g4.bOut = fc2b;
    g4.M = N; g4.K = NDIM; g4.Nc = NDIM; g4.act = 0; g4.has_rs = 0; g4.has_b = 1; g4.split_out = 0;
    for (int i = 0; i < 2; ++i) {
        g4.Ah[i] = Zh[i]; g4.Al[i] = Zl[i];
        g4.C[i] = out + (size_t)i * N * NDIM;
    }
    mfma_gemm_r<128><<<dim3(mgrid, 1, 2), 256, 0, stream>>>(g4);
}

// Round 2
// 683.211 us; speedup vs baseline: 1.1037x; 1.1037x over previous
//
#include <hip/hip_runtime.h>
#include <math.h>

#define NDIM 128   // in_dim = hid = out_dim
#define H2   256   // 2*hid
#define MAXG 2
#define TPE  8192  // edges per bin tile
#define NBKMAX 512 // max buckets (N <= 65536, 128 nodes/bucket)

typedef __attribute__((ext_vector_type(8))) short bf16x8;
typedef __attribute__((ext_vector_type(4))) float f32x4;

__device__ __forceinline__ unsigned short f2bf(float f) {
    unsigned int u = __float_as_uint(f);
    u += 0x7fffu + ((u >> 16) & 1u);           // RNE
    return (unsigned short)(u >> 16);
}
__device__ __forceinline__ float bf2f(unsigned short h) {
    return __uint_as_float(((unsigned int)h) << 16);
}
__device__ __forceinline__ void split2(float f, unsigned short& h, unsigned short& l) {
    h = f2bf(f);
    l = f2bf(f - bf2f(h));
}

// ================= binned edge build (no global atomics) =================
struct BinArgs {
    const int* src[MAXG]; const int* dst[MAXG];
    int* histD[MAXG]; int* histS[MAXG];     // [NT][NBK] counts -> global run offsets
    int* totD[MAXG];  int* baseD[MAXG];
    int* totS[MAXG];  int* baseS[MAXG];
    unsigned int* pairs[MAXG];              // dst-binned packed (dl<<16|src)
    unsigned short* srcS[MAXG];             // src-binned bare src ids
    int E[MAXG]; int NBK; int NT; int n;
};

__global__ __launch_bounds__(256) void binA(BinArgs a) {
    __shared__ int cntD[NBKMAX], cntS[NBKMAX];
    int g = blockIdx.y, t = blockIdx.x, tid = threadIdx.x;
    for (int b = tid; b < NBKMAX; b += 256) { cntD[b] = 0; cntS[b] = 0; }
    __syncthreads();
    int E = a.E[g];
    int base = t * TPE;
#pragma unroll
    for (int k = 0; k < TPE / 256; ++k) {
        int e = base + k * 256 + tid;
        if (e < E) {
            atomicAdd(&cntD[a.dst[g][e] >> 7], 1);
            atomicAdd(&cntS[a.src[g][e] >> 7], 1);
        }
    }
    __syncthreads();
    for (int b = tid; b < a.NBK; b += 256) {
        a.histD[g][t * a.NBK + b] = cntD[b];
        a.histS[g][t * a.NBK + b] = cntS[b];
    }
}

// fused: per-bucket totals + exclusive scan + rewrite hist to global run offsets
__global__ __launch_bounds__(512) void binB(BinArgs a) {
    int g = blockIdx.y, side = blockIdx.z;
    int* hist = side ? a.histS[g] : a.histD[g];
    int* tot  = side ? a.totS[g]  : a.totD[g];
    int* base = side ? a.baseS[g] : a.baseD[g];
    __shared__ int s[512];
    int b = threadIdx.x;
    int v = 0;
    if (b < a.NBK)
        for (int t = 0; t < a.NT; ++t) v += hist[t * a.NBK + b];
    s[b] = v;
    __syncthreads();
    for (int off = 1; off < 512; off <<= 1) {
        int u = (b >= off) ? s[b - off] : 0;
        __syncthreads();
        s[b] += u;
        __syncthreads();
    }
    int excl = s[b] - v;
    if (b < a.NBK) {
        tot[b] = v;
        base[b] = excl;
        int run = excl;
        for (int t = 0; t < a.NT; ++t) {
            int h = hist[t * a.NBK + b];
            hist[t * a.NBK + b] = run;
            run += h;
        }
    }
}

__global__ __launch_bounds__(256) void binC(BinArgs a) {
    __shared__ int offD[NBKMAX], offS[NBKMAX];
    int g = blockIdx.y, t = blockIdx.x, tid = threadIdx.x;
    for (int b = tid; b < a.NBK; b += 256) {
        offD[b] = a.histD[g][t * a.NBK + b];
        offS[b] = a.histS[g][t * a.NBK + b];
    }
    __syncthreads();
    int E = a.E[g];
    int base = t * TPE;
    unsigned int* pairs = a.pairs[g];
    unsigned short* ss = a.srcS[g];
#pragma unroll
    for (int k = 0; k < TPE / 256; ++k) {
        int e = base + k * 256 + tid;
        if (e < E) {
            int s = a.src[g][e], d = a.dst[g][e];
            int pos = atomicAdd(&offD[d >> 7], 1);
            pairs[pos] = ((unsigned int)(d & 127) << 16) | (unsigned int)s;
            int posS = atomicAdd(&offS[s >> 7], 1);
            ss[posS] = (unsigned short)s;
        }
    }
}

// fused: out-degree hist (-> ns) + per-bucket counting sort (-> CSR, nd, u16 edges)
struct FinArgs {
    const unsigned int* pairs[MAXG];
    const unsigned short* srcS[MAXG];
    const int* totD[MAXG]; const int* baseD[MAXG];
    const int* totS[MAXG]; const int* baseS[MAXG];
    int* row_ptr[MAXG]; int* row_end[MAXG];
    unsigned short* edge_srt[MAXG];
    float* ns[MAXG]; float* nd[MAXG];
    int n;
};

__global__ __launch_bounds__(256) void finalize(FinArgs a) {
    __shared__ int cnt[128], hist[128], scn[128], cur[128];
    int g = blockIdx.y, bkt = blockIdx.x, tid = threadIdx.x;
    if (tid < 128) { cnt[tid] = 0; hist[tid] = 0; }
    __syncthreads();
    // --- out-degree from src-binned segment -> ns ---
    {
        int base = a.baseS[g][bkt], tot = a.totS[g][bkt];
        const unsigned short* ss = a.srcS[g];
        for (int i = tid; i < tot; i += 256)
            atomicAdd(&cnt[ss[base + i] & 127], 1);
    }
    // --- in-degree hist of dst-binned pairs ---
    int cntE = a.totD[g][bkt], base = a.baseD[g][bkt];
    const unsigned int* pp = a.pairs[g] + base;
    for (int i = tid; i < cntE; i += 256)
        atomicAdd(&hist[pp[i] >> 16], 1);
    __syncthreads();
    if (tid < 128) {
        int node = bkt * 128 + tid;
        if (node < a.n) {
            int c = cnt[tid];
            a.ns[g][node] = rsqrtf((float)(c > 1 ? c : 1));
        }
        scn[tid] = hist[tid];
    }
    __syncthreads();
    for (int off = 1; off < 128; off <<= 1) {
        int v = (tid < 128 && tid >= off) ? scn[tid - off] : 0;
        __syncthreads();
        if (tid < 128) scn[tid] += v;
        __syncthreads();
    }
    if (tid < 128) {
        int incl = scn[tid];
        int h = hist[tid];
        cur[tid] = incl - h;
        int node = bkt * 128 + tid;
        if (node < a.n) {
            a.row_ptr[g][node] = base + incl - h;
            a.row_end[g][node] = base + incl;
            a.nd[g][node] = rsqrtf((float)(h > 1 ? h : 1));
        }
    }
    __syncthreads();
    for (int i = tid; i < cntE; i += 256) {
        unsigned int p = pp[i];
        int pos = atomicAdd(&cur[p >> 16], 1);
        a.edge_srt[g][base + pos] = (unsigned short)(p & 0xFFFF);
    }
}

// ===== gather-aggregate, half-wave/row =====
// use_sns: acc += X[src] * ns[src]  (prescale folded in; X = raw feat)
// else:    acc += X[src]            (X already has ns folded upstream)
struct GatherArgs {
    const float* X[MAXG];
    const int* row_ptr[MAXG]; const int* row_end[MAXG];
    const unsigned short* edge_src[MAXG];
    const float* nd[MAXG];
    const float* sns[MAXG];
    unsigned short* outH[MAXG]; unsigned short* outL[MAXG];
    const float* bias; int use_nd; int use_sns; int n;
};

__global__ __launch_bounds__(256) void gather_split_b(GatherArgs a) {
    int g = blockIdx.y;
    int half = threadIdx.x >> 5;
    int lane = threadIdx.x & 31;
    int r = blockIdx.x * 8 + half;
    if (r >= a.n) return;
    int j = a.row_ptr[g][r];
    int end = a.row_end[g][r];
    const unsigned short* ep = a.edge_src[g];
    const float* X = a.X[g];
    const float* sns = a.sns[g];
    int base = lane * 4;
    float4 acc = make_float4(0.f, 0.f, 0.f, 0.f);
    if (a.use_sns) {
        for (; j + 3 < end; j += 4) {
            int s0 = ep[j], s1 = ep[j + 1], s2 = ep[j + 2], s3 = ep[j + 3];
            float n0 = sns[s0], n1 = sns[s1], n2 = sns[s2], n3 = sns[s3];
            float4 v0 = *(const float4*)(X + (size_t)s0 * NDIM + base);
            float4 v1 = *(const float4*)(X + (size_t)s1 * NDIM + base);
            float4 v2 = *(const float4*)(X + (size_t)s2 * NDIM + base);
            float4 v3 = *(const float4*)(X + (size_t)s3 * NDIM + base);
            acc.x = fmaf(v0.x, n0, fmaf(v1.x, n1, fmaf(v2.x, n2, fmaf(v3.x, n3, acc.x))));
            acc.y = fmaf(v0.y, n0, fmaf(v1.y, n1, fmaf(v2.y, n2, fmaf(v3.y, n3, acc.y))));
            acc.z = fmaf(v0.z, n0, fmaf(v1.z, n1, fmaf(v2.z, n2, fmaf(v3.z, n3, acc.z))));
            acc.w = fmaf(v0.w, n0, fmaf(v1.w, n1, fmaf(v2.w, n2, fmaf(v3.w, n3, acc.w))));
        }
        for (; j < end; ++j) {
            int s0 = ep[j];
            float n0 = sns[s0];
            float4 v0 = *(const float4*)(X + (size_t)s0 * NDIM + base);
            acc.x = fmaf(v0.x, n0, acc.x); acc.y = fmaf(v0.y, n0, acc.y);
            acc.z = fmaf(v0.z, n0, acc.z); acc.w = fmaf(v0.w, n0, acc.w);
        }
    } else {
        for (; j + 3 < end; j += 4) {
            int s0 = ep[j], s1 = ep[j + 1], s2 = ep[j + 2], s3 = ep[j + 3];
            float4 v0 = *(const float4*)(X + (size_t)s0 * NDIM + base);
            float4 v1 = *(const float4*)(X + (size_t)s1 * NDIM + base);
            float4 v2 = *(const float4*)(X + (size_t)s2 * NDIM + base);
            float4 v3 = *(const float4*)(X + (size_t)s3 * NDIM + base);
            acc.x += v0.x + v1.x + v2.x + v3.x;
            acc.y += v0.y + v1.y + v2.y + v3.y;
            acc.z += v0.z + v1.z + v2.z + v3.z;
            acc.w += v0.w + v1.w + v2.w + v3.w;
        }
        for (; j < end; ++j) {
            int s0 = ep[j];
            float4 v0 = *(const float4*)(X + (size_t)s0 * NDIM + base);
            acc.x += v0.x; acc.y += v0.y; acc.z += v0.z; acc.w += v0.w;
        }
    }
    float v[4] = {acc.x, acc.y, acc.z, acc.w};
    if (a.use_nd) {
        float s = a.nd[g][r];
#pragma unroll
        for (int i = 0; i < 4; ++i)
            v[i] = fmaxf(v[i] * s + a.bias[base + i], 0.f);
    }
    unsigned short h[4], l[4];
#pragma unroll
    for (int i = 0; i < 4; ++i) split2(v[i], h[i], l[i]);
    *(ushort4*)(a.outH[g] + (size_t)r * NDIM + base) = make_ushort4(h[0], h[1], h[2], h[3]);
    *(ushort4*)(a.outL[g] + (size_t)r * NDIM + base) = make_ushort4(l[0], l[1], l[2], l[3]);
}

// ================= weight prep: all 4 weights, transposed + split =================
__global__ void wprep_all(const float* __restrict__ W1, const float* __restrict__ W2,
                          const float* __restrict__ F1, const float* __restrict__ F2,
                          unsigned short* __restrict__ W1h, unsigned short* __restrict__ W1l,
                          unsigned short* __restrict__ W2h, unsigned short* __restrict__ W2l,
                          unsigned short* __restrict__ F1h, unsigned short* __restrict__ F1l,
                          unsigned short* __restrict__ F2h, unsigned short* __restrict__ F2l) {
    int i = blockIdx.x * 256 + threadIdx.x;
    const float* Wsrc; unsigned short *Hd, *Ld; int K, Nc, idx;
    if (i < 32768)       { Wsrc = W1; Hd = W1h; Ld = W1l; K = 128; Nc = 256; idx = i; }
    else if (i < 65536)  { Wsrc = W2; Hd = W2h; Ld = W2l; K = 256; Nc = 128; idx = i - 32768; }
    else if (i < 81920)  { Wsrc = F1; Hd = F1h; Ld = F1l; K = 128; Nc = 128; idx = i - 65536; }
    else                 { Wsrc = F2; Hd = F2h; Ld = F2l; K = 128; Nc = 128; idx = i - 81920; }
    int k = idx / Nc, n = idx % Nc;
    unsigned short h, l;
    split2(Wsrc[idx], h, l);
    Hd[n * K + k] = h;
    Ld[n * K + k] = l;
}

// ====== split-bf16 MFMA GEMM: whole-K A staged in LDS (ONE barrier), B in regs ======
// A row-major [M][K] split h/l; B [Nc][K] transposed split h/l (<=128KB, L2-hot).
// Per block: 64 rows x 128 cols, 4 waves. LDS pad LDA=K+8 -> conflict-free b128.
struct GemmArgs {
    const unsigned short* Ah[MAXG]; const unsigned short* Al[MAXG];
    const unsigned short* Bh; const unsigned short* Bl;
    float* C[MAXG]; unsigned short* CH[MAXG]; unsigned short* CL[MAXG];
    const float* rsOut[MAXG]; const float* bOut;
    int M, K, Nc, act, has_rs, has_b, split_out;
};

template <int KT>
__global__ __launch_bounds__(256) void mfma_gemm_s(GemmArgs a) {
    constexpr int LDA = KT + 8;
    __shared__ __align__(16) unsigned short As_h[64 * LDA];
    __shared__ __align__(16) unsigned short As_l[64 * LDA];

    int g = blockIdx.z;
    const unsigned short* __restrict__ Ah_g = a.Ah[g];
    const unsigned short* __restrict__ Al_g = a.Al[g];
    const unsigned short* __restrict__ Bh = a.Bh;
    const unsigned short* __restrict__ Bl = a.Bl;

    int tid  = threadIdx.x;
    int wave = tid >> 6, lane = tid & 63;
    int quad = lane >> 4, l16 = lane & 15;
    int rowBase = blockIdx.x * 64;
    int colBase = blockIdx.y * 128;
    int M = a.M, Nc = a.Nc;

    f32x4 acc[4][2] = {};

    // B fragment addresses (per wave-column, per lane)
    size_t boff[2];
#pragma unroll
    for (int j = 0; j < 2; ++j)
        boff[j] = (size_t)(colBase + wave * 32 + j * 16 + l16) * KT + quad * 8;

    bf16x8 bh[2][4], bl[2][4];
    // issue pass-0 B loads first (L2-hot, latency hides under A staging)
#pragma unroll
    for (int j = 0; j < 2; ++j)
#pragma unroll
        for (int kt = 0; kt < 4; ++kt) {
            bh[j][kt] = *(const bf16x8*)(Bh + boff[j] + kt * 32);
            bl[j][kt] = *(const bf16x8*)(Bl + boff[j] + kt * 32);
        }

    // ---- stage the ENTIRE 64 x KT A-tile (h and l), single barrier ----
    constexpr int CPR = KT / 8;                 // 16B chunks per row
#pragma unroll
    for (int c0 = 0; c0 < 64 * CPR; c0 += 256) {
        int c = c0 + tid;
        int row = c / CPR;
        int col = (c - row * CPR) * 8;
        int gr = rowBase + row;
        uint4 vh = make_uint4(0, 0, 0, 0), vl = make_uint4(0, 0, 0, 0);
        if (gr < M) {
            vh = *(const uint4*)(Ah_g + (size_t)gr * KT + col);
            vl = *(const uint4*)(Al_g + (size_t)gr * KT + col);
        }
        *(uint4*)(As_h + row * LDA + col) = vh;
        *(uint4*)(As_l + row * LDA + col) = vl;
    }
    __syncthreads();

    // ---- pure ds_read -> MFMA stream, no further barriers ----
#pragma unroll
    for (int p = 0; p < KT / 128; ++p) {
        if (p) {
#pragma unroll
            for (int j = 0; j < 2; ++j)
#pragma unroll
                for (int kt = 0; kt < 4; ++kt) {
                    bh[j][kt] = *(const bf16x8*)(Bh + boff[j] + p * 128 + kt * 32);
                    bl[j][kt] = *(const bf16x8*)(Bl + boff[j] + p * 128 + kt * 32);
                }
        }
#pragma unroll
        for (int kt = 0; kt < 4; ++kt) {
            int kc = p * 128 + kt * 32 + quad * 8;
            bf16x8 af[4], alf[4];
#pragma unroll
            for (int i = 0; i < 4; ++i) {
                af[i]  = *(const bf16x8*)(As_h + (i * 16 + l16) * LDA + kc);
                alf[i] = *(const bf16x8*)(As_l + (i * 16 + l16) * LDA + kc);
            }
#pragma unroll
            for (int i = 0; i < 4; ++i)
#pragma unroll
                for (int j = 0; j < 2; ++j) {
                    acc[i][j] = __builtin_amdgcn_mfma_f32_16x16x32_bf16(af[i],  bh[j][kt], acc[i][j], 0, 0, 0);
                    acc[i][j] = __builtin_amdgcn_mfma_f32_16x16x32_bf16(alf[i], bh[j][kt], acc[i][j], 0, 0, 0);
                    acc[i][j] = __builtin_amdgcn_mfma_f32_16x16x32_bf16(af[i],  bl[j][kt], acc[i][j], 0, 0, 0);
                }
        }
    }

    // epilogue: C/D layout col=lane&15, row=quad*4+reg
#pragma unroll
    for (int i = 0; i < 4; ++i) {
#pragma unroll
        for (int r = 0; r < 4; ++r) {
            int row = rowBase + i * 16 + quad * 4 + r;
            if (row >= M) continue;
            float rs = a.has_rs ? a.rsOut[g][row] : 1.0f;
#pragma unroll
            for (int j = 0; j < 2; ++j) {
                int col = colBase + wave * 32 + j * 16 + l16;
                float v = acc[i][j][r] * rs;
                if (a.has_b) v += a.bOut[col];
                if (a.act == 1) v = fmaxf(v, 0.f);
                else if (a.act == 2) v = v > 0.f ? v : expm1f(v);
                if (a.split_out) {
                    unsigned short h, l;
                    split2(v, h, l);
                    a.CH[g][(size_t)row * Nc + col] = h;
                    a.CL[g][(size_t)row * Nc + col] = l;
                } else {
                    a.C[g][(size_t)row * Nc + col] = v;
                }
            }
        }
    }
}

extern "C" void kernel_launch(void* const* d_in, const int* in_sizes, int n_in,
                              void* d_out, int out_size, void* d_ws, size_t ws_size,
                              hipStream_t stream) {
    const float* feat[2] = {(const float*)d_in[0], (const float*)d_in[1]};
    const int*   ei[2]   = {(const int*)d_in[2], (const int*)d_in[3]};
    const float* W1   = (const float*)d_in[4];
    const float* b1   = (const float*)d_in[5];
    const float* W2   = (const float*)d_in[6];
    const float* b2   = (const float*)d_in[7];
    const float* fc1W = (const float*)d_in[8];
    const float* fc1b = (const float*)d_in[9];
    const float* fc2W = (const float*)d_in[10];
    const float* fc2b = (const float*)d_in[11];
    int N = in_sizes[0] / NDIM;     // 50000 (< 65536: u16 node-id packing valid)
    float* out = (float*)d_out;

    int Emax = 0;
    for (int g = 0; g < 2; ++g) { int E = in_sizes[2 + g] / 2; if (E > Emax) Emax = E; }
    int NBK = (N + 127) / 128;
    int NT  = (Emax + TPE - 1) / TPE;

    // ---- workspace layout ----
    char* p = (char*)d_ws;
    float* ns_[2]; float* nd_[2];
    for (int i = 0; i < 2; ++i) { ns_[i] = (float*)p; p += (size_t)N * 4; }
    for (int i = 0; i < 2; ++i) { nd_[i] = (float*)p; p += (size_t)N * 4; }
    int* rp_[2]; int* re_[2]; unsigned short* esrt_[2];
    for (int i = 0; i < 2; ++i) { rp_[i] = (int*)p; p += (size_t)N * 4; }
    for (int i = 0; i < 2; ++i) { re_[i] = (int*)p; p += (size_t)N * 4; }
    for (int i = 0; i < 2; ++i) { esrt_[i] = (unsigned short*)p; p += (size_t)Emax * 2; }
    unsigned short* R1[2]; unsigned short* R2[2];
    for (int i = 0; i < 2; ++i) { R1[i] = (unsigned short*)p; p += (size_t)N * NDIM * 2 * 2; }
    for (int i = 0; i < 2; ++i) { R2[i] = (unsigned short*)p; p += (size_t)N * H2 * 2 * 2; }
    unsigned short* W1th = (unsigned short*)p; p += (size_t)NDIM * H2 * 2;
    unsigned short* W1tl = (unsigned short*)p; p += (size_t)NDIM * H2 * 2;
    unsigned short* W2th = (unsigned short*)p; p += (size_t)H2 * NDIM * 2;
    unsigned short* W2tl = (unsigned short*)p; p += (size_t)H2 * NDIM * 2;
    unsigned short* f1th = (unsigned short*)p; p += (size_t)NDIM * NDIM * 2;
    unsigned short* f1tl = (unsigned short*)p; p += (size_t)NDIM * NDIM * 2;
    unsigned short* f2th = (unsigned short*)p; p += (size_t)NDIM * NDIM * 2;
    unsigned short* f2tl = (unsigned short*)p; p += (size_t)NDIM * NDIM * 2;
    int* tb = (int*)p; p += (size_t)2 * 4 * NBK * 4;   // totD/baseD/totS/baseS per graph

    // aliases with disjoint lifetimes (all within R1/R2):
    //  - histD/histS at R2[i]+0 (dead after binC); pairs at R2[i]+1MB (dead after finalize)
    //  - srcS at R1[i] (dead after finalize; gather1 then writes A1 into R1)
    //  - gather1 reads feat directly (ns folded per-edge) so R2 is untouched until gemm1
    int* histD_[2]; int* histS_[2]; unsigned int* pairs_[2]; unsigned short* srcS_[2];
    for (int i = 0; i < 2; ++i) {
        histD_[i] = (int*)R2[i];
        histS_[i] = (int*)R2[i] + (size_t)NT * NBK;
        pairs_[i] = (unsigned int*)((char*)R2[i] + (1 << 20));  // 1MB offset > hist tables
        srcS_[i]  = (unsigned short*)R1[i];
    }

    BinArgs ba = {};
    ba.NBK = NBK; ba.NT = NT; ba.n = N;
    for (int i = 0; i < 2; ++i) {
        int E = in_sizes[2 + i] / 2;
        ba.src[i] = ei[i]; ba.dst[i] = ei[i] + E; ba.E[i] = E;
        ba.histD[i] = histD_[i]; ba.histS[i] = histS_[i];
        ba.totD[i]  = tb + (size_t)i * 4 * NBK;
        ba.baseD[i] = tb + (size_t)i * 4 * NBK + NBK;
        ba.totS[i]  = tb + (size_t)i * 4 * NBK + 2 * NBK;
        ba.baseS[i] = tb + (size_t)i * 4 * NBK + 3 * NBK;
        ba.pairs[i] = pairs_[i]; ba.srcS[i] = srcS_[i];
    }

    // ---- weight prep + binned edge build ----
    wprep_all<<<384, 256, 0, stream>>>(W1, W2, fc1W, fc2W,
                                       W1th, W1tl, W2th, W2tl, f1th, f1tl, f2th, f2tl);
    binA<<<dim3(NT, 2), 256, 0, stream>>>(ba);
    binB<<<dim3(1, 2, 2), 512, 0, stream>>>(ba);
    binC<<<dim3(NT, 2), 256, 0, stream>>>(ba);

    FinArgs fa = {};
    fa.n = N;
    for (int i = 0; i < 2; ++i) {
        fa.pairs[i] = pairs_[i]; fa.srcS[i] = srcS_[i];
        fa.totD[i] = ba.totD[i]; fa.baseD[i] = ba.baseD[i];
        fa.totS[i] = ba.totS[i]; fa.baseS[i] = ba.baseS[i];
        fa.row_ptr[i] = rp_[i]; fa.row_end[i] = re_[i];
        fa.edge_srt[i] = esrt_[i];
        fa.ns[i] = ns_[i]; fa.nd[i] = nd_[i];
    }
    finalize<<<dim3(NBK, 2), 256, 0, stream>>>(fa);

    // ---- per-graph buffer aliases ----
    unsigned short *A1h[2], *A1l[2], *X1h[2], *X1l[2], *Gh[2], *Gl[2], *Zh[2], *Zl[2];
    float* T[2];
    for (int i = 0; i < 2; ++i) {
        A1h[i] = R1[i]; A1l[i] = R1[i] + (size_t)N * NDIM;
        T[i]   = (float*)R1[i];
        Zh[i]  = R1[i]; Zl[i]  = R1[i] + (size_t)N * NDIM;
        X1h[i] = R2[i]; X1l[i] = R2[i] + (size_t)N * H2;
        Gh[i]  = R2[i]; Gl[i]  = R2[i] + (size_t)N * NDIM;
    }

    int ggrid = (N + 7) / 8;
    int mgrid = (N + 63) / 64;

    // ---- gather1: A1 = split(sum feat[src] * ns[src]) ----
    GatherArgs ga = {};
    ga.n = N; ga.use_nd = 0; ga.use_sns = 1; ga.bias = b2;
    for (int i = 0; i < 2; ++i) {
        ga.X[i] = feat[i];
        ga.row_ptr[i] = rp_[i]; ga.row_end[i] = re_[i]; ga.edge_src[i] = esrt_[i];
        ga.nd[i] = nd_[i]; ga.sns[i] = ns_[i];
        ga.outH[i] = A1h[i]; ga.outL[i] = A1l[i];
    }
    gather_split_b<<<dim3(ggrid, 2), 256, 0, stream>>>(ga);

    // ---- gemm1: X1 = relu(A1 @ W1 * nd + b1), split out ----
    GemmArgs g1 = {};
    g1.Bh = W1th; g1.Bl = W1tl; g1.bOut = b1;
    g1.M = N; g1.K = NDIM; g1.Nc = H2; g1.act = 1; g1.has_rs = 1; g1.has_b = 1; g1.split_out = 1;
    for (int i = 0; i < 2; ++i) {
        g1.Ah[i] = A1h[i]; g1.Al[i] = A1l[i];
        g1.CH[i] = X1h[i]; g1.CL[i] = X1l[i]; g1.rsOut[i] = nd_[i];
    }
    mfma_gemm_s<128><<<dim3(mgrid, H2 / 128, 2), 256, 0, stream>>>(g1);

    // ---- gemm2: T = (X1 @ W2) * ns, fp32 out (ns folded here so gather2 is a pure sum) ----
    GemmArgs g2 = {};
    g2.Bh = W2th; g2.Bl = W2tl;
    g2.M = N; g2.K = H2; g2.Nc = NDIM; g2.act = 0; g2.has_rs = 1; g2.has_b = 0; g2.split_out = 0;
    for (int i = 0; i < 2; ++i) {
        g2.Ah[i] = X1h[i]; g2.Al[i] = X1l[i]; g2.C[i] = T[i]; g2.rsOut[i] = ns_[i];
    }
    mfma_gemm_s<256><<<dim3(mgrid, 1, 2), 256, 0, stream>>>(g2);

    // ---- gather2: G = split(relu(sum T[src] * nd + b2)) ----
    GatherArgs gb = ga;
    gb.use_nd = 1; gb.use_sns = 0;
    for (int i = 0; i < 2; ++i) {
        gb.X[i] = T[i];
        gb.outH[i] = Gh[i]; gb.outL[i] = Gl[i];
    }
    gather_split_b<<<dim3(ggrid, 2), 256, 0, stream>>>(gb);

    // ---- gemm3: Z = elu(G @ fc1W + fc1b), split out ----
    GemmArgs g3 = {};
    g3.Bh = f1th; g3.Bl = f1tl; g3.bOut = fc1b;
    g3.M = N; g3.K = NDIM; g3.Nc = NDIM; g3.act = 2; g3.has_rs = 0; g3.has_b = 1; g3.split_out = 1;
    for (int i = 0; i < 2; ++i) {
        g3.Ah[i] = Gh[i]; g3.Al[i] = Gl[i];
        g3.CH[i] = Zh[i]; g3.CL[i] = Zl[i];
    }
    mfma_gemm_s<128><<<dim3(mgrid, 1, 2), 256, 0, stream>>>(g3);

    // ---- gemm4: out = Z @ fc2W + fc2b, fp32 out ----
    GemmArgs g4 = {};
    g4.Bh = f2th; g4.Bl = f2tl; g4.bOut = fc2b;
    g4.M = N; g4.K = NDIM; g4.Nc = NDIM; g4.act = 0; g4.has_rs = 0; g4.has_b = 1; g4.split_out = 0;
    for (int i = 0; i < 2; ++i) {
        g4.Ah[i] = Zh[i]; g4.Al[i] = Zl[i];
        g4.C[i] = out + (size_t)i * N * NDIM;
    }
    mfma_gemm_s<128><<<dim3(mgrid, 1, 2), 256, 0, stream>>>(g4);
}

// Round 3
// 590.523 us; speedup vs baseline: 1.2770x; 1.1570x over previous
//
#include <hip/hip_runtime.h>
#include <math.h>

#define NDIM 128   // in_dim = hid = out_dim
#define H2   256   // 2*hid
#define MAXG 2
#define TPE  8192  // edges per bin tile
#define NBKMAX 512 // max buckets (N <= 65536, 128 nodes/bucket)

typedef __attribute__((ext_vector_type(8))) short bf16x8;
typedef __attribute__((ext_vector_type(4))) float f32x4;

__device__ __forceinline__ unsigned short f2bf(float f) {
    unsigned int u = __float_as_uint(f);
    u += 0x7fffu + ((u >> 16) & 1u);           // RNE
    return (unsigned short)(u >> 16);
}
__device__ __forceinline__ float bf2f(unsigned short h) {
    return __uint_as_float(((unsigned int)h) << 16);
}
__device__ __forceinline__ void split2(float f, unsigned short& h, unsigned short& l) {
    h = f2bf(f);
    l = f2bf(f - bf2f(h));
}

// ================= binned edge build (no global atomics) =================
struct BinArgs {
    const int* src[MAXG]; const int* dst[MAXG];
    int* histD[MAXG]; int* histS[MAXG];     // [NT][NBK] counts -> global run offsets
    int* totD[MAXG];  int* baseD[MAXG];
    int* totS[MAXG];  int* baseS[MAXG];
    unsigned int* pairs[MAXG];              // dst-binned packed (dl<<16|src)
    unsigned short* srcS[MAXG];             // src-binned bare src ids
    int E[MAXG]; int NBK; int NT; int n;
};

__global__ __launch_bounds__(256) void binA(BinArgs a) {
    __shared__ int cntD[NBKMAX], cntS[NBKMAX];
    int g = blockIdx.y, t = blockIdx.x, tid = threadIdx.x;
    for (int b = tid; b < NBKMAX; b += 256) { cntD[b] = 0; cntS[b] = 0; }
    __syncthreads();
    int E = a.E[g];
    int base = t * TPE;
#pragma unroll
    for (int k = 0; k < TPE / 256; ++k) {
        int e = base + k * 256 + tid;
        if (e < E) {
            atomicAdd(&cntD[a.dst[g][e] >> 7], 1);
            atomicAdd(&cntS[a.src[g][e] >> 7], 1);
        }
    }
    __syncthreads();
    for (int b = tid; b < a.NBK; b += 256) {
        a.histD[g][t * a.NBK + b] = cntD[b];
        a.histS[g][t * a.NBK + b] = cntS[b];
    }
}

// fused: per-bucket totals + exclusive scan + rewrite hist to global run offsets
__global__ __launch_bounds__(512) void binB(BinArgs a) {
    int g = blockIdx.y, side = blockIdx.z;
    int* hist = side ? a.histS[g] : a.histD[g];
    int* tot  = side ? a.totS[g]  : a.totD[g];
    int* base = side ? a.baseS[g] : a.baseD[g];
    __shared__ int s[512];
    int b = threadIdx.x;
    int v = 0;
    if (b < a.NBK)
        for (int t = 0; t < a.NT; ++t) v += hist[t * a.NBK + b];
    s[b] = v;
    __syncthreads();
    for (int off = 1; off < 512; off <<= 1) {
        int u = (b >= off) ? s[b - off] : 0;
        __syncthreads();
        s[b] += u;
        __syncthreads();
    }
    int excl = s[b] - v;
    if (b < a.NBK) {
        tot[b] = v;
        base[b] = excl;
        int run = excl;
        for (int t = 0; t < a.NT; ++t) {
            int h = hist[t * a.NBK + b];
            hist[t * a.NBK + b] = run;
            run += h;
        }
    }
}

__global__ __launch_bounds__(256) void binC(BinArgs a) {
    __shared__ int offD[NBKMAX], offS[NBKMAX];
    int g = blockIdx.y, t = blockIdx.x, tid = threadIdx.x;
    for (int b = tid; b < a.NBK; b += 256) {
        offD[b] = a.histD[g][t * a.NBK + b];
        offS[b] = a.histS[g][t * a.NBK + b];
    }
    __syncthreads();
    int E = a.E[g];
    int base = t * TPE;
    unsigned int* pairs = a.pairs[g];
    unsigned short* ss = a.srcS[g];
#pragma unroll
    for (int k = 0; k < TPE / 256; ++k) {
        int e = base + k * 256 + tid;
        if (e < E) {
            int s = a.src[g][e], d = a.dst[g][e];
            int pos = atomicAdd(&offD[d >> 7], 1);
            pairs[pos] = ((unsigned int)(d & 127) << 16) | (unsigned int)s;
            int posS = atomicAdd(&offS[s >> 7], 1);
            ss[posS] = (unsigned short)s;
        }
    }
}

// fused: out-degree hist (-> ns) + per-bucket counting sort (-> CSR, nd, u16 edges)
struct FinArgs {
    const unsigned int* pairs[MAXG];
    const unsigned short* srcS[MAXG];
    const int* totD[MAXG]; const int* baseD[MAXG];
    const int* totS[MAXG]; const int* baseS[MAXG];
    int* row_ptr[MAXG]; int* row_end[MAXG];
    unsigned short* edge_srt[MAXG];
    float* ns[MAXG]; float* nd[MAXG];
    int n;
};

__global__ __launch_bounds__(256) void finalize(FinArgs a) {
    __shared__ int cnt[128], hist[128], scn[128], cur[128];
    int g = blockIdx.y, bkt = blockIdx.x, tid = threadIdx.x;
    if (tid < 128) { cnt[tid] = 0; hist[tid] = 0; }
    __syncthreads();
    // --- out-degree from src-binned segment -> ns ---
    {
        int base = a.baseS[g][bkt], tot = a.totS[g][bkt];
        const unsigned short* ss = a.srcS[g];
        for (int i = tid; i < tot; i += 256)
            atomicAdd(&cnt[ss[base + i] & 127], 1);
    }
    // --- in-degree hist of dst-binned pairs ---
    int cntE = a.totD[g][bkt], base = a.baseD[g][bkt];
    const unsigned int* pp = a.pairs[g] + base;
    for (int i = tid; i < cntE; i += 256)
        atomicAdd(&hist[pp[i] >> 16], 1);
    __syncthreads();
    if (tid < 128) {
        int node = bkt * 128 + tid;
        if (node < a.n) {
            int c = cnt[tid];
            a.ns[g][node] = rsqrtf((float)(c > 1 ? c : 1));
        }
        scn[tid] = hist[tid];
    }
    __syncthreads();
    for (int off = 1; off < 128; off <<= 1) {
        int v = (tid < 128 && tid >= off) ? scn[tid - off] : 0;
        __syncthreads();
        if (tid < 128) scn[tid] += v;
        __syncthreads();
    }
    if (tid < 128) {
        int incl = scn[tid];
        int h = hist[tid];
        cur[tid] = incl - h;
        int node = bkt * 128 + tid;
        if (node < a.n) {
            a.row_ptr[g][node] = base + incl - h;
            a.row_end[g][node] = base + incl;
            a.nd[g][node] = rsqrtf((float)(h > 1 ? h : 1));
        }
    }
    __syncthreads();
    for (int i = tid; i < cntE; i += 256) {
        unsigned int p = pp[i];
        int pos = atomicAdd(&cur[p >> 16], 1);
        a.edge_srt[g][base + pos] = (unsigned short)(p & 0xFFFF);
    }
}

// ===== gather-aggregate, half-wave/row =====
// use_sns: acc += X[src] * ns[src]  (prescale folded in; X = raw feat)
// else:    acc += X[src]            (X already has ns folded upstream)
struct GatherArgs {
    const float* X[MAXG];
    const int* row_ptr[MAXG]; const int* row_end[MAXG];
    const unsigned short* edge_src[MAXG];
    const float* nd[MAXG];
    const float* sns[MAXG];
    unsigned short* outH[MAXG]; unsigned short* outL[MAXG];
    const float* bias; int use_nd; int use_sns; int n;
};

__global__ __launch_bounds__(256) void gather_split_b(GatherArgs a) {
    int g = blockIdx.y;
    int half = threadIdx.x >> 5;
    int lane = threadIdx.x & 31;
    int r = blockIdx.x * 8 + half;
    if (r >= a.n) return;
    int j = a.row_ptr[g][r];
    int end = a.row_end[g][r];
    const unsigned short* ep = a.edge_src[g];
    const float* X = a.X[g];
    const float* sns = a.sns[g];
    int base = lane * 4;
    float4 acc = make_float4(0.f, 0.f, 0.f, 0.f);
    if (a.use_sns) {
        for (; j + 3 < end; j += 4) {
            int s0 = ep[j], s1 = ep[j + 1], s2 = ep[j + 2], s3 = ep[j + 3];
            float n0 = sns[s0], n1 = sns[s1], n2 = sns[s2], n3 = sns[s3];
            float4 v0 = *(const float4*)(X + (size_t)s0 * NDIM + base);
            float4 v1 = *(const float4*)(X + (size_t)s1 * NDIM + base);
            float4 v2 = *(const float4*)(X + (size_t)s2 * NDIM + base);
            float4 v3 = *(const float4*)(X + (size_t)s3 * NDIM + base);
            acc.x = fmaf(v0.x, n0, fmaf(v1.x, n1, fmaf(v2.x, n2, fmaf(v3.x, n3, acc.x))));
            acc.y = fmaf(v0.y, n0, fmaf(v1.y, n1, fmaf(v2.y, n2, fmaf(v3.y, n3, acc.y))));
            acc.z = fmaf(v0.z, n0, fmaf(v1.z, n1, fmaf(v2.z, n2, fmaf(v3.z, n3, acc.z))));
            acc.w = fmaf(v0.w, n0, fmaf(v1.w, n1, fmaf(v2.w, n2, fmaf(v3.w, n3, acc.w))));
        }
        for (; j < end; ++j) {
            int s0 = ep[j];
            float n0 = sns[s0];
            float4 v0 = *(const float4*)(X + (size_t)s0 * NDIM + base);
            acc.x = fmaf(v0.x, n0, acc.x); acc.y = fmaf(v0.y, n0, acc.y);
            acc.z = fmaf(v0.z, n0, acc.z); acc.w = fmaf(v0.w, n0, acc.w);
        }
    } else {
        for (; j + 3 < end; j += 4) {
            int s0 = ep[j], s1 = ep[j + 1], s2 = ep[j + 2], s3 = ep[j + 3];
            float4 v0 = *(const float4*)(X + (size_t)s0 * NDIM + base);
            float4 v1 = *(const float4*)(X + (size_t)s1 * NDIM + base);
            float4 v2 = *(const float4*)(X + (size_t)s2 * NDIM + base);
            float4 v3 = *(const float4*)(X + (size_t)s3 * NDIM + base);
            acc.x += v0.x + v1.x + v2.x + v3.x;
            acc.y += v0.y + v1.y + v2.y + v3.y;
            acc.z += v0.z + v1.z + v2.z + v3.z;
            acc.w += v0.w + v1.w + v2.w + v3.w;
        }
        for (; j < end; ++j) {
            int s0 = ep[j];
            float4 v0 = *(const float4*)(X + (size_t)s0 * NDIM + base);
            acc.x += v0.x; acc.y += v0.y; acc.z += v0.z; acc.w += v0.w;
        }
    }
    float v[4] = {acc.x, acc.y, acc.z, acc.w};
    if (a.use_nd) {
        float s = a.nd[g][r];
#pragma unroll
        for (int i = 0; i < 4; ++i)
            v[i] = fmaxf(v[i] * s + a.bias[base + i], 0.f);
    }
    unsigned short h[4], l[4];
#pragma unroll
    for (int i = 0; i < 4; ++i) split2(v[i], h[i], l[i]);
    *(ushort4*)(a.outH[g] + (size_t)r * NDIM + base) = make_ushort4(h[0], h[1], h[2], h[3]);
    *(ushort4*)(a.outL[g] + (size_t)r * NDIM + base) = make_ushort4(l[0], l[1], l[2], l[3]);
}

// ================= weight prep: all 4 weights, transposed + split =================
__global__ void wprep_all(const float* __restrict__ W1, const float* __restrict__ W2,
                          const float* __restrict__ F1, const float* __restrict__ F2,
                          unsigned short* __restrict__ W1h, unsigned short* __restrict__ W1l,
                          unsigned short* __restrict__ W2h, unsigned short* __restrict__ W2l,
                          unsigned short* __restrict__ F1h, unsigned short* __restrict__ F1l,
                          unsigned short* __restrict__ F2h, unsigned short* __restrict__ F2l) {
    int i = blockIdx.x * 256 + threadIdx.x;
    const float* Wsrc; unsigned short *Hd, *Ld; int K, Nc, idx;
    if (i < 32768)       { Wsrc = W1; Hd = W1h; Ld = W1l; K = 128; Nc = 256; idx = i; }
    else if (i < 65536)  { Wsrc = W2; Hd = W2h; Ld = W2l; K = 256; Nc = 128; idx = i - 32768; }
    else if (i < 81920)  { Wsrc = F1; Hd = F1h; Ld = F1l; K = 128; Nc = 128; idx = i - 65536; }
    else                 { Wsrc = F2; Hd = F2h; Ld = F2l; K = 128; Nc = 128; idx = i - 81920; }
    int k = idx / Nc, n = idx % Nc;
    unsigned short h, l;
    split2(Wsrc[idx], h, l);
    Hd[n * K + k] = h;
    Ld[n * K + k] = l;
}

// ====== FUSED back-to-back split-bf16 MFMA GEMM ======
// Per block: 64 rows. Pass 1: A(64xK1,split) @ B1(K1xN1) -> act -> hidden tile
// (64xN1, split) restaged in LDS (union with A stage). Pass 2: hidden @ B2(N1x128)
// -> C (fp32, 64x128). Eliminates the hidden-layer global round trip entirely.
// B1/B2 are [cols][K] transposed split weights, L2-resident; frags loaded per-kt.
struct FusedArgs {
    const unsigned short* Ah[MAXG]; const unsigned short* Al[MAXG];
    const unsigned short* B1h; const unsigned short* B1l;
    const unsigned short* B2h; const unsigned short* B2l;
    const float* rs1[MAXG];  // per-row scale after pass1 (nd), optional
    const float* rs2[MAXG];  // per-row scale after pass2 (ns), optional
    const float* b1v;        // pass1 bias, optional
    const float* b2v;        // pass2 bias, optional
    float* C[MAXG];
    int M, has_rs1, has_rs2, has_b1, has_b2;
};

template <int K1, int N1, int ACT1>   // ACT1: 1=relu, 2=elu
__global__ __launch_bounds__(256) void fused_gemm2(FusedArgs a) {
    constexpr int LDA = K1 + 8;
    constexpr int LDX = N1 + 8;
    constexpr int SH_A = 64 * LDA;                 // shorts, per h/l plane
    constexpr int SH_X = 64 * LDX;
    constexpr int SH = (2 * SH_A > 2 * SH_X) ? 2 * SH_A : 2 * SH_X;
    __shared__ __align__(16) unsigned short S[SH];
    unsigned short* As_h = S;
    unsigned short* As_l = S + SH_A;
    unsigned short* Xs_h = S;                      // union: A dead before X written
    unsigned short* Xs_l = S + SH_X;

    int g = blockIdx.y;
    const unsigned short* __restrict__ Ah_g = a.Ah[g];
    const unsigned short* __restrict__ Al_g = a.Al[g];

    int tid  = threadIdx.x;
    int wave = tid >> 6, lane = tid & 63;
    int quad = lane >> 4, l16 = lane & 15;
    int rowBase = blockIdx.x * 64;
    int M = a.M;

    // ---- stage A tile (64 x K1, h+l) ----
    constexpr int CPR = K1 / 8;
#pragma unroll
    for (int c0 = 0; c0 < 64 * CPR; c0 += 256) {
        int c = c0 + tid;
        int row = c / CPR;
        int col = (c % CPR) * 8;
        int gr = rowBase + row;
        uint4 vh = make_uint4(0, 0, 0, 0), vl = make_uint4(0, 0, 0, 0);
        if (gr < M) {
            vh = *(const uint4*)(Ah_g + (size_t)gr * K1 + col);
            vl = *(const uint4*)(Al_g + (size_t)gr * K1 + col);
        }
        *(uint4*)(As_h + row * LDA + col) = vh;
        *(uint4*)(As_l + row * LDA + col) = vl;
    }
    __syncthreads();

    // ---- pass 1: 64 x N1 (each wave owns N1/4 contiguous cols) ----
    constexpr int J1 = N1 / 64;
    int wcol1 = wave * (N1 / 4);
    f32x4 acc1[4][J1] = {};
#pragma unroll
    for (int kt = 0; kt < K1 / 32; ++kt) {
        int kc = kt * 32 + quad * 8;
        bf16x8 af[4], alf[4];
#pragma unroll
        for (int i = 0; i < 4; ++i) {
            af[i]  = *(const bf16x8*)(As_h + (i * 16 + l16) * LDA + kc);
            alf[i] = *(const bf16x8*)(As_l + (i * 16 + l16) * LDA + kc);
        }
        bf16x8 bh_[J1], bl_[J1];
#pragma unroll
        for (int j = 0; j < J1; ++j) {
            size_t bo = (size_t)(wcol1 + j * 16 + l16) * K1 + kt * 32 + quad * 8;
            bh_[j] = *(const bf16x8*)(a.B1h + bo);
            bl_[j] = *(const bf16x8*)(a.B1l + bo);
        }
#pragma unroll
        for (int i = 0; i < 4; ++i)
#pragma unroll
            for (int j = 0; j < J1; ++j) {
                acc1[i][j] = __builtin_amdgcn_mfma_f32_16x16x32_bf16(af[i],  bh_[j], acc1[i][j], 0, 0, 0);
                acc1[i][j] = __builtin_amdgcn_mfma_f32_16x16x32_bf16(alf[i], bh_[j], acc1[i][j], 0, 0, 0);
                acc1[i][j] = __builtin_amdgcn_mfma_f32_16x16x32_bf16(af[i],  bl_[j], acc1[i][j], 0, 0, 0);
            }
    }
    __syncthreads();   // all waves done reading As before Xs overwrite

    // ---- epilogue 1: act -> split -> LDS hidden tile ----
    const float* rs1p = a.has_rs1 ? a.rs1[g] : nullptr;
#pragma unroll
    for (int i = 0; i < 4; ++i) {
#pragma unroll
        for (int r = 0; r < 4; ++r) {
            int row  = i * 16 + quad * 4 + r;
            int grow = rowBase + row;
            float rs = 1.0f;
            if (rs1p) rs = (grow < M) ? rs1p[grow] : 0.0f;
#pragma unroll
            for (int j = 0; j < J1; ++j) {
                int col = wcol1 + j * 16 + l16;
                float v = acc1[i][j][r] * rs;
                if (a.has_b1) v += a.b1v[col];
                if (ACT1 == 1) v = fmaxf(v, 0.f);
                else           v = v > 0.f ? v : expm1f(v);
                unsigned short h, l;
                split2(v, h, l);
                Xs_h[row * LDX + col] = h;
                Xs_l[row * LDX + col] = l;
            }
        }
    }
    __syncthreads();

    // ---- pass 2: hidden(64 x N1) @ B2(N1 x 128); each wave owns 32 cols ----
    int wcol2 = wave * 32;
    f32x4 acc2[4][2] = {};
#pragma unroll
    for (int kt = 0; kt < N1 / 32; ++kt) {
        int kc = kt * 32 + quad * 8;
        bf16x8 xf[4], xlf[4];
#pragma unroll
        for (int i = 0; i < 4; ++i) {
            xf[i]  = *(const bf16x8*)(Xs_h + (i * 16 + l16) * LDX + kc);
            xlf[i] = *(const bf16x8*)(Xs_l + (i * 16 + l16) * LDX + kc);
        }
        bf16x8 bh_[2], bl_[2];
#pragma unroll
        for (int j = 0; j < 2; ++j) {
            size_t bo = (size_t)(wcol2 + j * 16 + l16) * N1 + kt * 32 + quad * 8;
            bh_[j] = *(const bf16x8*)(a.B2h + bo);
            bl_[j] = *(const bf16x8*)(a.B2l + bo);
        }
#pragma unroll
        for (int i = 0; i < 4; ++i)
#pragma unroll
            for (int j = 0; j < 2; ++j) {
                acc2[i][j] = __builtin_amdgcn_mfma_f32_16x16x32_bf16(xf[i],  bh_[j], acc2[i][j], 0, 0, 0);
                acc2[i][j] = __builtin_amdgcn_mfma_f32_16x16x32_bf16(xlf[i], bh_[j], acc2[i][j], 0, 0, 0);
                acc2[i][j] = __builtin_amdgcn_mfma_f32_16x16x32_bf16(xf[i],  bl_[j], acc2[i][j], 0, 0, 0);
            }
    }

    // ---- epilogue 2: fp32 out ----
    const float* rs2p = a.has_rs2 ? a.rs2[g] : nullptr;
#pragma unroll
    for (int i = 0; i < 4; ++i) {
#pragma unroll
        for (int r = 0; r < 4; ++r) {
            int grow = rowBase + i * 16 + quad * 4 + r;
            if (grow >= M) continue;
            float rs = rs2p ? rs2p[grow] : 1.0f;
#pragma unroll
            for (int j = 0; j < 2; ++j) {
                int col = wcol2 + j * 16 + l16;
                float v = acc2[i][j][r] * rs;
                if (a.has_b2) v += a.b2v[col];
                a.C[g][(size_t)grow * NDIM + col] = v;
            }
        }
    }
}

extern "C" void kernel_launch(void* const* d_in, const int* in_sizes, int n_in,
                              void* d_out, int out_size, void* d_ws, size_t ws_size,
                              hipStream_t stream) {
    const float* feat[2] = {(const float*)d_in[0], (const float*)d_in[1]};
    const int*   ei[2]   = {(const int*)d_in[2], (const int*)d_in[3]};
    const float* W1   = (const float*)d_in[4];
    const float* b1   = (const float*)d_in[5];
    const float* W2   = (const float*)d_in[6];
    const float* b2   = (const float*)d_in[7];
    const float* fc1W = (const float*)d_in[8];
    const float* fc1b = (const float*)d_in[9];
    const float* fc2W = (const float*)d_in[10];
    const float* fc2b = (const float*)d_in[11];
    int N = in_sizes[0] / NDIM;     // 50000 (< 65536: u16 node-id packing valid)
    float* out = (float*)d_out;

    int Emax = 0;
    for (int g = 0; g < 2; ++g) { int E = in_sizes[2 + g] / 2; if (E > Emax) Emax = E; }
    int NBK = (N + 127) / 128;
    int NT  = (Emax + TPE - 1) / TPE;

    // ---- workspace layout ----
    char* p = (char*)d_ws;
    float* ns_[2]; float* nd_[2];
    for (int i = 0; i < 2; ++i) { ns_[i] = (float*)p; p += (size_t)N * 4; }
    for (int i = 0; i < 2; ++i) { nd_[i] = (float*)p; p += (size_t)N * 4; }
    int* rp_[2]; int* re_[2]; unsigned short* esrt_[2];
    for (int i = 0; i < 2; ++i) { rp_[i] = (int*)p; p += (size_t)N * 4; }
    for (int i = 0; i < 2; ++i) { re_[i] = (int*)p; p += (size_t)N * 4; }
    for (int i = 0; i < 2; ++i) { esrt_[i] = (unsigned short*)p; p += (size_t)Emax * 2; }
    unsigned short* R1[2]; unsigned short* R2[2];
    for (int i = 0; i < 2; ++i) { R1[i] = (unsigned short*)p; p += (size_t)N * NDIM * 2 * 2; }
    for (int i = 0; i < 2; ++i) { R2[i] = (unsigned short*)p; p += (size_t)N * H2 * 2 * 2; }
    unsigned short* W1th = (unsigned short*)p; p += (size_t)NDIM * H2 * 2;
    unsigned short* W1tl = (unsigned short*)p; p += (size_t)NDIM * H2 * 2;
    unsigned short* W2th = (unsigned short*)p; p += (size_t)H2 * NDIM * 2;
    unsigned short* W2tl = (unsigned short*)p; p += (size_t)H2 * NDIM * 2;
    unsigned short* f1th = (unsigned short*)p; p += (size_t)NDIM * NDIM * 2;
    unsigned short* f1tl = (unsigned short*)p; p += (size_t)NDIM * NDIM * 2;
    unsigned short* f2th = (unsigned short*)p; p += (size_t)NDIM * NDIM * 2;
    unsigned short* f2tl = (unsigned short*)p; p += (size_t)NDIM * NDIM * 2;
    int* tb = (int*)p; p += (size_t)2 * 4 * NBK * 4;   // totD/baseD/totS/baseS per graph

    // aliases with disjoint lifetimes:
    //  - histD/histS at R2[i]+0 (dead after binC); pairs at R2[i]+1MB (dead after finalize)
    //  - srcS at R1[i] (dead after finalize; gather1 then writes A1 into R1)
    //  - T (fp32, N*128) at R2[i][0 : N*256 shorts]; G (h+l) after it — disjoint
    int* histD_[2]; int* histS_[2]; unsigned int* pairs_[2]; unsigned short* srcS_[2];
    for (int i = 0; i < 2; ++i) {
        histD_[i] = (int*)R2[i];
        histS_[i] = (int*)R2[i] + (size_t)NT * NBK;
        pairs_[i] = (unsigned int*)((char*)R2[i] + (1 << 20));  // 1MB offset > hist tables
        srcS_[i]  = (unsigned short*)R1[i];
    }

    BinArgs ba = {};
    ba.NBK = NBK; ba.NT = NT; ba.n = N;
    for (int i = 0; i < 2; ++i) {
        int E = in_sizes[2 + i] / 2;
        ba.src[i] = ei[i]; ba.dst[i] = ei[i] + E; ba.E[i] = E;
        ba.histD[i] = histD_[i]; ba.histS[i] = histS_[i];
        ba.totD[i]  = tb + (size_t)i * 4 * NBK;
        ba.baseD[i] = tb + (size_t)i * 4 * NBK + NBK;
        ba.totS[i]  = tb + (size_t)i * 4 * NBK + 2 * NBK;
        ba.baseS[i] = tb + (size_t)i * 4 * NBK + 3 * NBK;
        ba.pairs[i] = pairs_[i]; ba.srcS[i] = srcS_[i];
    }

    // ---- weight prep + binned edge build ----
    wprep_all<<<384, 256, 0, stream>>>(W1, W2, fc1W, fc2W,
                                       W1th, W1tl, W2th, W2tl, f1th, f1tl, f2th, f2tl);
    binA<<<dim3(NT, 2), 256, 0, stream>>>(ba);
    binB<<<dim3(1, 2, 2), 512, 0, stream>>>(ba);
    binC<<<dim3(NT, 2), 256, 0, stream>>>(ba);

    FinArgs fa = {};
    fa.n = N;
    for (int i = 0; i < 2; ++i) {
        fa.pairs[i] = pairs_[i]; fa.srcS[i] = srcS_[i];
        fa.totD[i] = ba.totD[i]; fa.baseD[i] = ba.baseD[i];
        fa.totS[i] = ba.totS[i]; fa.baseS[i] = ba.baseS[i];
        fa.row_ptr[i] = rp_[i]; fa.row_end[i] = re_[i];
        fa.edge_srt[i] = esrt_[i];
        fa.ns[i] = ns_[i]; fa.nd[i] = nd_[i];
    }
    finalize<<<dim3(NBK, 2), 256, 0, stream>>>(fa);

    // ---- per-graph buffer aliases ----
    unsigned short *A1h[2], *A1l[2], *Gh[2], *Gl[2];
    float* T[2];
    for (int i = 0; i < 2; ++i) {
        A1h[i] = R1[i]; A1l[i] = R1[i] + (size_t)N * NDIM;
        T[i]   = (float*)R2[i];                         // N*128 fp32 = N*256 shorts
        Gh[i]  = R2[i] + (size_t)N * 256;
        Gl[i]  = R2[i] + (size_t)N * 256 + (size_t)N * NDIM;
    }

    int ggrid = (N + 7) / 8;
    int mgrid = (N + 63) / 64;

    // ---- gather1: A1 = split(sum feat[src] * ns[src]) ----
    GatherArgs ga = {};
    ga.n = N; ga.use_nd = 0; ga.use_sns = 1; ga.bias = b2;
    for (int i = 0; i < 2; ++i) {
        ga.X[i] = feat[i];
        ga.row_ptr[i] = rp_[i]; ga.row_end[i] = re_[i]; ga.edge_src[i] = esrt_[i];
        ga.nd[i] = nd_[i]; ga.sns[i] = ns_[i];
        ga.outH[i] = A1h[i]; ga.outL[i] = A1l[i];
    }
    gather_split_b<<<dim3(ggrid, 2), 256, 0, stream>>>(ga);

    // ---- fused12: T = (relu(A1@W1 * nd + b1) @ W2) * ns, fp32 out ----
    FusedArgs f12 = {};
    f12.B1h = W1th; f12.B1l = W1tl; f12.B2h = W2th; f12.B2l = W2tl;
    f12.b1v = b1; f12.has_b1 = 1; f12.has_b2 = 0;
    f12.has_rs1 = 1; f12.has_rs2 = 1;
    f12.M = N;
    for (int i = 0; i < 2; ++i) {
        f12.Ah[i] = A1h[i]; f12.Al[i] = A1l[i];
        f12.rs1[i] = nd_[i]; f12.rs2[i] = ns_[i];
        f12.C[i] = T[i];
    }
    fused_gemm2<128, 256, 1><<<dim3(mgrid, 2), 256, 0, stream>>>(f12);

    // ---- gather2: G = split(relu(sum T[src] * nd + b2)) ----
    GatherArgs gb = ga;
    gb.use_nd = 1; gb.use_sns = 0;
    for (int i = 0; i < 2; ++i) {
        gb.X[i] = T[i];
        gb.outH[i] = Gh[i]; gb.outL[i] = Gl[i];
    }
    gather_split_b<<<dim3(ggrid, 2), 256, 0, stream>>>(gb);

    // ---- fused34: out = elu(G@fc1W + fc1b) @ fc2W + fc2b, fp32 out ----
    FusedArgs f34 = {};
    f34.B1h = f1th; f34.B1l = f1tl; f34.B2h = f2th; f34.B2l = f2tl;
    f34.b1v = fc1b; f34.has_b1 = 1; f34.b2v = fc2b; f34.has_b2 = 1;
    f34.has_rs1 = 0; f34.has_rs2 = 0;
    f34.M = N;
    for (int i = 0; i < 2; ++i) {
        f34.Ah[i] = Gh[i]; f34.Al[i] = Gl[i];
        f34.C[i] = out + (size_t)i * N * NDIM;
    }
    fused_gemm2<128, 128, 2><<<dim3(mgrid, 2), 256, 0, stream>>>(f34);
}